// Round 5
// baseline (196.160 us; speedup 1.0000x reference)
//
#include <hip/hip_runtime.h>

#define SEQ  4096
#define DMODEL 1024
#define QTOT 16384           // B*S
#define QSCALE 0.18033688011112042f   // (1/sqrt(64)) * log2(e), folded into Q

typedef __bf16 bf16x8 __attribute__((ext_vector_type(8)));
typedef unsigned short u16x8 __attribute__((ext_vector_type(8)));
typedef float f32x4 __attribute__((ext_vector_type(4)));

// ---------- helpers ----------
static __device__ __forceinline__ unsigned short f2bfbits(float f) {
    unsigned int u = __builtin_bit_cast(unsigned int, f);
    unsigned int lsb = (u >> 16) & 1u;
    u += 0x7fffu + lsb;                      // round-to-nearest-even
    return (unsigned short)(u >> 16);
}

static __device__ __forceinline__ bf16x8 ld_frag(const unsigned short* p) {
    uint4 u = *reinterpret_cast<const uint4*>(p);
    return __builtin_bit_cast(bf16x8, u);
}

// ---------- kernel 1: weights -> bf16, pre-swizzled into MFMA fragment order ----------
// WtS: frag(kc,nt) at ushort offset (kc*12+nt)*512; lane l owns [l*8, l*8+8)
// element j of lane l = W^T[nt*16 + (l&15)][kc*32 + (l>>4)*8 + j]
__global__ void prep_weights(const float* __restrict__ Wq,
                             const float* __restrict__ Wk,
                             const float* __restrict__ Wv,
                             unsigned short* __restrict__ WtS) {
    int o = blockIdx.x * 256 + threadIdx.x;      // 192*1024 total
    int f = o >> 9, q = o & 511;
    int lane = q >> 3, j = q & 7;
    int kc = f / 12, nt = f - kc * 12;
    int n = nt * 16 + (lane & 15);
    int k = kc * 32 + (lane >> 4) * 8 + j;
    float v;
    if (n < 64)       v = Wq[k * 64 + n];
    else if (n < 128) v = Wk[k * 64 + (n - 64)];
    else              v = Wv[k * 64 + (n - 128)];
    WtS[o] = f2bfbits(v);
}

// ---------- kernel 2: QKV projection, LDS double-buffered, intra-block N-split ----------
// grid 512 x 256 thr. Block = 32 tokens, full K=1024, all 192 outs.
// wave w: tokhalf = w&1 (16 tokens), nhalf = w>>1 (6 of 12 n-fragments).
// emb tile [32 tok][32 k] fp32 staged per step; chunk-XOR swizzle for conflict-free reads.
__global__ __launch_bounds__(256) void proj(
        const float* __restrict__ emb, const unsigned short* __restrict__ WtS,
        const float* __restrict__ bq, const float* __restrict__ bk,
        const float* __restrict__ bv,
        unsigned short* __restrict__ Qb, unsigned short* __restrict__ Kb,
        unsigned short* __restrict__ VT) {
    __shared__ __align__(16) float Et[2][32 * 32];

    const int tid = threadIdx.x;
    const int w = tid >> 6, lane = tid & 63;
    const int c = lane & 15, qd = lane >> 4;
    const int tokhalf = w & 1, nhalf = w >> 1;
    const int mbase = blockIdx.x * 32;

    // staging: thread loads 16 B of emb[tok][4*(kc^ (tok&7)) ..] per step
    const int stok = tid >> 3, skc = tid & 7;
    const float* sp = emb + (size_t)(mbase + stok) * DMODEL + ((skc ^ (stok & 7)) << 2);
    float* dp0 = &Et[0][tid * 4];
    float* dp1 = &Et[1][tid * 4];

    // A-fragment read position (swizzled chunks)
    const int arow = tokhalf * 16 + c;
    const int pk0 = ((2 * qd) ^ (arow & 7)) * 4;
    const int pk1 = ((2 * qd + 1) ^ (arow & 7)) * 4;

    const unsigned short* wp = WtS + (nhalf * 6) * 512 + lane * 8;

    f32x4 acc[6];
#pragma unroll
    for (int i = 0; i < 6; i++) acc[i] = (f32x4){0.f, 0.f, 0.f, 0.f};

    // prologue: stage step 0, preload W frags for step 0
    float4 sreg = *reinterpret_cast<const float4*>(sp);
    *reinterpret_cast<float4*>(dp0) = sreg;
    bf16x8 wc[6], wn[6];
#pragma unroll
    for (int nt = 0; nt < 6; nt++) wc[nt] = ld_frag(wp + nt * 512);

    for (int i = 0; i < 32; i++) {
        __syncthreads();                         // buf[i&1] + W(i) ready for all
        float4 nreg;
        if (i < 31)
            nreg = *reinterpret_cast<const float4*>(sp + (i + 1) * 32);
        if (i < 31) {
#pragma unroll
            for (int nt = 0; nt < 6; nt++)
                wn[nt] = ld_frag(wp + (size_t)(i + 1) * 6144 + nt * 512);
        } else {
#pragma unroll
            for (int nt = 0; nt < 6; nt++) wn[nt] = wc[nt];
        }

        const float* eb = &Et[i & 1][arow * 32];
        float4 a0 = *reinterpret_cast<const float4*>(eb + pk0);
        float4 a1 = *reinterpret_cast<const float4*>(eb + pk1);
        u16x8 at;
        at[0] = f2bfbits(a0.x); at[1] = f2bfbits(a0.y);
        at[2] = f2bfbits(a0.z); at[3] = f2bfbits(a0.w);
        at[4] = f2bfbits(a1.x); at[5] = f2bfbits(a1.y);
        at[6] = f2bfbits(a1.z); at[7] = f2bfbits(a1.w);
        bf16x8 af = __builtin_bit_cast(bf16x8, at);

#pragma unroll
        for (int nt = 0; nt < 6; nt++)
            acc[nt] = __builtin_amdgcn_mfma_f32_16x16x32_bf16(af, wc[nt], acc[nt], 0, 0, 0);

        if (i < 31)
            *reinterpret_cast<float4*>((i & 1) ? dp0 : dp1) = nreg;
#pragma unroll
        for (int nt = 0; nt < 6; nt++) wc[nt] = wn[nt];
    }

    // epilogue: +bias, Q pre-scaled, bf16 stores (V transposed)
#pragma unroll
    for (int nt = 0; nt < 6; nt++) {
        int n = nhalf * 96 + nt * 16 + c;
        float bias = (n < 64) ? bq[n] : (n < 128) ? bk[n - 64] : bv[n - 128];
        float fac = (n < 64) ? QSCALE : 1.0f;
#pragma unroll
        for (int r = 0; r < 4; r++) {
            int token = mbase + tokhalf * 16 + qd * 4 + r;
            unsigned short bits = f2bfbits((acc[nt][r] + bias) * fac);
            if (n < 64)        Qb[(size_t)token * 64 + n] = bits;
            else if (n < 128)  Kb[(size_t)token * 64 + (n - 64)] = bits;
            else {
                int bb = token >> 12, ss = token & 4095;
                VT[((size_t)bb * 64 + (n - 128)) * SEQ + ss] = bits;
            }
        }
    }
}

// ---------- kernel 3: barrier-free flash attention, q-tile 32 ----------
// grid 512 (4b x 128 q-blocks, XCD-pinned by b); 512 thr = 8 waves, 4 waves/SIMD.
// Wave w owns t-slice [w*512, w*512+512) for all 32 q-rows; end tree-reduce.
__global__ __launch_bounds__(512, 4) void attn(
        const unsigned short* __restrict__ Qb, const unsigned short* __restrict__ Kb,
        const unsigned short* __restrict__ VT, float* __restrict__ out) {
    __shared__ __align__(16) unsigned short Pl[8][32 * 72];  // per-wave P; aliased as reduce buf
    __shared__ float l_all[8][32];

    const int tid = threadIdx.x;
    const int w = tid >> 6, lane = tid & 63;
    const int c = lane & 15, qd = lane >> 4;
    const int g3 = blockIdx.x & 7;               // XCD pin: b*2 + (qblk&1)
    const int b = g3 >> 1;
    const int qblk = ((blockIdx.x >> 3) << 1) | (g3 & 1);
    const int qbase = qblk * 32;
    const int tstart = w * 512;

    bf16x8 aq0[2], aq1[2];                       // Q pre-scaled by QSCALE at proj
#pragma unroll
    for (int qs = 0; qs < 2; qs++) {
        const unsigned short* Qp = Qb + ((size_t)(b << 12) + qbase + qs * 16 + c) * 64 + qd * 8;
        aq0[qs] = ld_frag(Qp);
        aq1[qs] = ld_frag(Qp + 32);
    }

    f32x4 acc[8];                                // [qs][nt]
#pragma unroll
    for (int i = 0; i < 8; i++) acc[i] = (f32x4){0.f, 0.f, 0.f, 0.f};
    float lsum[2][4];
#pragma unroll
    for (int qs = 0; qs < 2; qs++)
#pragma unroll
        for (int r = 0; r < 4; r++) lsum[qs][r] = 0.f;

    unsigned short* myP = &Pl[w][0];

#pragma unroll 2
    for (int it = 0; it < 8; it++) {
        const int t0 = tstart + it * 64;
        const unsigned short* Kt = Kb + ((size_t)(b << 12) + t0) * 64;

        bf16x8 bk0[4], bk1[4];                   // K B-frags straight from global (L2)
#pragma unroll
        for (int ts = 0; ts < 4; ts++) {
            bk0[ts] = ld_frag(Kt + (ts * 16 + c) * 64 + qd * 8);
            bk1[ts] = ld_frag(Kt + (ts * 16 + c) * 64 + 32 + qd * 8);
        }

#pragma unroll
        for (int qs = 0; qs < 2; qs++) {
            f32x4 sc[4];
#pragma unroll
            for (int ts = 0; ts < 4; ts++) {
                f32x4 z = (f32x4){0.f, 0.f, 0.f, 0.f};
                z = __builtin_amdgcn_mfma_f32_16x16x32_bf16(aq0[qs], bk0[ts], z, 0, 0, 0);
                z = __builtin_amdgcn_mfma_f32_16x16x32_bf16(aq1[qs], bk1[ts], z, 0, 0, 0);
                sc[ts] = z;
            }
#pragma unroll
            for (int ts = 0; ts < 4; ts++)
#pragma unroll
                for (int r = 0; r < 4; r++) {
                    float p = __builtin_amdgcn_exp2f(sc[ts][r]);
                    lsum[qs][r] += p;
                    myP[(qs * 16 + qd * 4 + r) * 72 + ts * 16 + c] = f2bfbits(p);
                }
        }

        bf16x8 bv0[4], bv1[4];                   // V B-frags straight from global (L2)
#pragma unroll
        for (int nt = 0; nt < 4; nt++) {
            const unsigned short* Vp = VT + (((size_t)b * 64 + nt * 16 + c) << 12) + t0 + qd * 8;
            bv0[nt] = ld_frag(Vp);
            bv1[nt] = ld_frag(Vp + 32);
        }

#pragma unroll
        for (int qs = 0; qs < 2; qs++) {
            bf16x8 ap0 = ld_frag(&myP[(qs * 16 + c) * 72 + qd * 8]);
            bf16x8 ap1 = ld_frag(&myP[(qs * 16 + c) * 72 + 32 + qd * 8]);
#pragma unroll
            for (int nt = 0; nt < 4; nt++) {
                acc[qs * 4 + nt] = __builtin_amdgcn_mfma_f32_16x16x32_bf16(ap0, bv0[nt], acc[qs * 4 + nt], 0, 0, 0);
                acc[qs * 4 + nt] = __builtin_amdgcn_mfma_f32_16x16x32_bf16(ap1, bv1[nt], acc[qs * 4 + nt], 0, 0, 0);
            }
        }
    }

    // l reduction across the 16 column lanes
#pragma unroll
    for (int off = 1; off < 16; off <<= 1)
#pragma unroll
        for (int qs = 0; qs < 2; qs++)
#pragma unroll
            for (int r = 0; r < 4; r++) lsum[qs][r] += __shfl_xor(lsum[qs][r], off);
    if (c == 0) {
#pragma unroll
        for (int qs = 0; qs < 2; qs++)
#pragma unroll
            for (int r = 0; r < 4; r++)
                l_all[w][qs * 16 + qd * 4 + r] = lsum[qs][r];
    }

    // tree-reduce acc over 8 waves; buffer aliases Pl (slot = 2176 floats, lane stride 34)
    float* red = (float*)&Pl[0][0];
    __syncthreads();
    if (w >= 4) {
        float* rp = red + (w - 4) * 2176 + lane * 34;
#pragma unroll
        for (int i = 0; i < 8; i++) *reinterpret_cast<f32x4*>(rp + i * 4) = acc[i];
    }
    __syncthreads();
    if (w < 4) {
        float* rp = red + w * 2176 + lane * 34;
#pragma unroll
        for (int i = 0; i < 8; i++) acc[i] += *reinterpret_cast<const f32x4*>(rp + i * 4);
    }
    __syncthreads();
    if (w == 2 || w == 3) {
        float* rp = red + (w - 2) * 2176 + lane * 34;
#pragma unroll
        for (int i = 0; i < 8; i++) *reinterpret_cast<f32x4*>(rp + i * 4) = acc[i];
    }
    __syncthreads();
    if (w < 2) {
        float* rp = red + w * 2176 + lane * 34;
#pragma unroll
        for (int i = 0; i < 8; i++) acc[i] += *reinterpret_cast<const f32x4*>(rp + i * 4);
    }
    __syncthreads();
    if (w == 1) {
        float* rp = red + lane * 34;
#pragma unroll
        for (int i = 0; i < 8; i++) *reinterpret_cast<f32x4*>(rp + i * 4) = acc[i];
    }
    __syncthreads();
    if (w == 0) {
        float* rp = red + lane * 34;
#pragma unroll
        for (int i = 0; i < 8; i++) acc[i] += *reinterpret_cast<const f32x4*>(rp + i * 4);
#pragma unroll
        for (int qs = 0; qs < 2; qs++)
#pragma unroll
            for (int r = 0; r < 4; r++) {
                int q = qs * 16 + qd * 4 + r;
                float l = 0.f;
#pragma unroll
                for (int ww = 0; ww < 8; ww++) l += l_all[ww][q];
                float inv = 1.0f / l;
                size_t row = (size_t)(b << 12) + qbase + q;
#pragma unroll
                for (int nt = 0; nt < 4; nt++)
                    out[row * 64 + nt * 16 + c] = acc[qs * 4 + nt][r] * inv;
            }
    }
}

// ---------- launch ----------
extern "C" void kernel_launch(void* const* d_in, const int* in_sizes, int n_in,
                              void* d_out, int out_size, void* d_ws, size_t ws_size,
                              hipStream_t stream) {
    const float* emb = (const float*)d_in[0];
    const float* Wq  = (const float*)d_in[1];
    const float* bq  = (const float*)d_in[2];
    const float* Wk  = (const float*)d_in[3];
    const float* bk  = (const float*)d_in[4];
    const float* Wv  = (const float*)d_in[5];
    const float* bv  = (const float*)d_in[6];
    float* out = (float*)d_out;

    unsigned short* ws = (unsigned short*)d_ws;
    unsigned short* WtS = ws;                      // 192*1024
    unsigned short* Qb = ws + 192 * 1024;          // QTOT*64
    unsigned short* Kb = Qb + QTOT * 64;
    unsigned short* VT = Kb + QTOT * 64;           // [b][v][t]

    prep_weights<<<768, 256, 0, stream>>>(Wq, Wk, Wv, WtS);
    proj<<<512, 256, 0, stream>>>(emb, WtS, bq, bk, bv, Qb, Kb, VT);
    attn<<<512, 512, 0, stream>>>(Qb, Kb, VT, out);
}